// Round 5
// baseline (1475.360 us; speedup 1.0000x reference)
//
#include <hip/hip_runtime.h>
#include <hip/hip_bf16.h>
#include <cstdint>
#include <cstddef>

#define N_TOT 10000
#define CDIM  128
#define TK    50
#define NHID_ 256
#define NCLS  10
#define GAMMA_REG 0.01f
#define BN_EPS 1e-5f

typedef float f32x4 __attribute__((ext_vector_type(4)));
typedef short s16x8 __attribute__((ext_vector_type(8)));

__device__ __forceinline__ float waveSumF(float v){
  #pragma unroll
  for (int o=32;o;o>>=1) v += __shfl_xor(v,o,64);
  return v;
}
__device__ __forceinline__ float waveMaxF(float v){
  #pragma unroll
  for (int o=32;o;o>>=1) v = fmaxf(v,__shfl_xor(v,o,64));
  return v;
}
__device__ __forceinline__ int waveSumI(int v){
  #pragma unroll
  for (int o=32;o;o>>=1) v += __shfl_xor(v,o,64);
  return v;
}
__device__ __forceinline__ ushort bfh(float f){
  __hip_bfloat16 h = __float2bfloat16(f);          // RNE
  return *reinterpret_cast<ushort*>(&h);
}
__device__ __forceinline__ float bf2f(ushort u){
  __hip_bfloat16 h = *reinterpret_cast<__hip_bfloat16*>(&u);
  return __bfloat162float(h);
}
__device__ __forceinline__ void gload16(const void* g, void* l){
  __builtin_amdgcn_global_load_lds(
      (const __attribute__((address_space(1))) void*)g,
      (__attribute__((address_space(3))) void*)l, 16, 0, 0);
}

// ---------------- generic 64x64 fp32 GEMM: C = A[MxK] @ B[KxN] (+bias) ----------
template<bool BIAS>
__global__ __launch_bounds__(256) void gemm64(const float* __restrict__ A,
                                              const float* __restrict__ B,
                                              const float* __restrict__ bias,
                                              float* __restrict__ C,
                                              int M, int N, int K){
  constexpr int BK=32;
  __shared__ float As[BK][64+4];
  __shared__ float Bs[BK][64+4];
  const int tid = threadIdx.x;
  const int bm = blockIdx.y*64, bn = blockIdx.x*64;
  const int tm = (tid>>4)<<2;
  const int tn = (tid&15)<<2;
  float acc[4][4] = {};
  for (int k0=0;k0<K;k0+=BK){
    #pragma unroll
    for (int i=0;i<2;++i){
      int fi = tid + i*256;
      int r  = fi>>3;
      int c4 = fi&7;
      float4 v = make_float4(0,0,0,0);
      int gr = bm + r;
      if (gr < M) v = *(const float4*)(A + (size_t)gr*K + k0 + (c4<<2));
      As[(c4<<2)+0][r]=v.x; As[(c4<<2)+1][r]=v.y; As[(c4<<2)+2][r]=v.z; As[(c4<<2)+3][r]=v.w;
    }
    #pragma unroll
    for (int i=0;i<2;++i){
      int fi = tid + i*256;
      int r  = fi>>4;
      int c4 = fi&15;
      float4 v = *(const float4*)(B + (size_t)(k0+r)*N + bn + (c4<<2));
      *(float4*)&Bs[r][c4<<2] = v;
    }
    __syncthreads();
    #pragma unroll
    for (int kk=0;kk<BK;++kk){
      float a[4], b[4];
      *(float4*)a = *(const float4*)&As[kk][tm];
      *(float4*)b = *(const float4*)&Bs[kk][tn];
      #pragma unroll
      for (int i=0;i<4;++i)
        #pragma unroll
        for (int j=0;j<4;++j) acc[i][j] = fmaf(a[i], b[j], acc[i][j]);
    }
    __syncthreads();
  }
  #pragma unroll
  for (int i=0;i<4;++i){
    int gr = bm+tm+i;
    if (gr < M){
      float4 o; o.x=acc[i][0]; o.y=acc[i][1]; o.z=acc[i][2]; o.w=acc[i][3];
      if (BIAS){
        o.x += bias[bn+tn+0]; o.y += bias[bn+tn+1];
        o.z += bias[bn+tn+2]; o.w += bias[bn+tn+3];
      }
      *(float4*)(C + (size_t)gr*N + bn + tn) = o;
    }
  }
}

// ---------------- per-chunk BatchNorm (training stats, biased var), in place ----
__global__ void bn_kernel(float* __restrict__ feat, const float* __restrict__ g,
                          const float* __restrict__ b){
  int chunk = blockIdx.x;
  int c = threadIdx.x;
  float* base = feat + (size_t)chunk*100*CDIM;
  float s=0.f, s2=0.f;
  for (int r=0;r<100;++r){ float v = base[r*CDIM+c]; s += v; s2 += v*v; }
  float mu  = s * 0.01f;
  float var = s2 * 0.01f - mu*mu;
  float sc  = g[c] * rsqrtf(var + BN_EPS);
  float sh  = b[c] - mu*sc;
  for (int r=0;r<100;++r){ base[r*CDIM+c] = base[r*CDIM+c]*sc + sh; }
}

// ------- split feat into bf16 hi/lo (plain: fh/fl, a-scaled: gh/gl) + p, xn ----
__global__ __launch_bounds__(256) void featsplit(const float* __restrict__ feat,
                                                 const float* __restrict__ aS,
                                                 ushort* __restrict__ fh, ushort* __restrict__ fl,
                                                 ushort* __restrict__ gh, ushort* __restrict__ gl,
                                                 float* __restrict__ p, float* __restrict__ xn){
  int wave = threadIdx.x>>6, lane = threadIdx.x&63;
  int row = blockIdx.x*4 + wave;
  const float2 f = ((const float2*)(feat + (size_t)row*CDIM))[lane];
  const float2 a = ((const float2*)aS)[lane];
  float gx = f.x*a.x, gy = f.y*a.y;

  ushort2 v;
  size_t o = (size_t)row*64 + lane;
  v.x = bfh(f.x); v.y = bfh(f.y);
  ((ushort2*)fh)[o] = v;
  ushort2 vl; vl.x = bfh(f.x - bf2f(v.x)); vl.y = bfh(f.y - bf2f(v.y));
  ((ushort2*)fl)[o] = vl;
  ushort2 w; w.x = bfh(gx); w.y = bfh(gy);
  ((ushort2*)gh)[o] = w;
  ushort2 wl2; wl2.x = bfh(gx - bf2f(w.x)); wl2.y = bfh(gy - bf2f(w.y));
  ((ushort2*)gl)[o] = wl2;

  float sp = gx*f.x + gy*f.y;
  float sx = f.x*f.x + f.y*f.y;
  sp = waveSumF(sp); sx = waveSumF(sx);
  if (lane==0){ p[row]=sp; xn[row]=sx; }
}

// -------- scores[i][j] = relu(p_i + p_j + b - 2 * (g_i . f_j)), split-bf16 MFMA -
// LDS-staged via global_load_lds (width 16), T2 XOR swizzle (both sides),
// 128x128 tile, full K=128, nontemporal score stores, XCD-chunked grid swizzle.
__global__ __launch_bounds__(256, 1) void score_mfma(const ushort* __restrict__ fh,
                                                     const ushort* __restrict__ fl,
                                                     const ushort* __restrict__ gh,
                                                     const ushort* __restrict__ gl,
                                                     const float* __restrict__ p,
                                                     const float* __restrict__ bS,
                                                     float* __restrict__ scores){
  extern __shared__ ushort lds[];   // 65536 ushorts = 128 KiB
  // byte sections: Agh 0, Agl 32768, Bfh 65536, Bfl 98304; each [128 rows][256 B]
  const int tid  = threadIdx.x;
  const int lane = tid & 63;
  const int wave = tid >> 6;
  const int wm = wave >> 1, wn = wave & 1;

  // bijective XCD-chunk swizzle (m204): nwg=6241, 8 XCDs; col-major tile map
  const int nwg = 6241, q = nwg >> 3, r = nwg & 7;   // q=780, r=1
  int bid = blockIdx.x;
  int xcd = bid & 7, loc = bid >> 3;
  int wid = (xcd < r ? xcd*(q+1) : r*(q+1) + (xcd-r)*q) + loc;
  const int bxt = wid / 79;          // column tile (contiguous band per XCD)
  const int byt = wid % 79;          // row tile
  const int bm = byt*128;
  const int bn = bxt*128;

  // ---- stage: linear LDS dest, inverse-swizzled global source (rule 21) ----
  // chunk cs in [0,2048) per section: row = cs>>4, dst byte in row = (cs&15)*16,
  // src byte = dst ^ ((row&7)<<4).
  #define STAGE(SRC, ROWBASE, SECOFF_USHORT)                                  \
    { _Pragma("unroll")                                                       \
      for (int it=0; it<8; ++it){                                             \
        int cs  = it*256 + tid;                                               \
        int row = cs >> 4;                                                    \
        int kbd = (cs & 15) << 4;                                             \
        int kbs = kbd ^ ((row & 7) << 4);                                     \
        int rg  = (ROWBASE) + row; rg = (rg < N_TOT ? rg : N_TOT-1);          \
        gload16(SRC + (size_t)rg*CDIM + (kbs >> 1),                           \
                lds + (SECOFF_USHORT) + cs*8);                                \
      } }
  STAGE(gh, bm, 0)
  STAGE(gl, bm, 16384)
  STAGE(fh, bn, 32768)
  STAGE(fl, bn, 49152)
  #undef STAGE
  __syncthreads();   // compiler emits vmcnt(0) drain before barrier

  const int lr = lane & 15;          // row-in-16 / output col
  const int kq = lane >> 4;          // k-quarter
  const char* ldsb = (const char*)lds;
  f32x4 acc[4][4] = {};

  #pragma unroll
  for (int ks=0; ks<4; ++ks){
    const int kbyte = ks*64 + kq*16;
    s16x8 ah[4], al[4], bh[4], bl[4];
    #pragma unroll
    for (int i=0;i<4;++i){
      int ra = wm*64 + i*16 + lr;
      int ca = wn*64 + i*16 + lr;
      int oa = ra*256 + (kbyte ^ ((ra & 7) << 4));
      int ob = ca*256 + (kbyte ^ ((ca & 7) << 4));
      ah[i] = *(const s16x8*)(ldsb + oa);
      al[i] = *(const s16x8*)(ldsb + 32768 + oa);
      bh[i] = *(const s16x8*)(ldsb + 65536 + ob);
      bl[i] = *(const s16x8*)(ldsb + 98304 + ob);
    }
    #pragma unroll
    for (int i=0;i<4;++i)
      #pragma unroll
      for (int j=0;j<4;++j){
        acc[i][j] = __builtin_amdgcn_mfma_f32_16x16x32_bf16(ah[i], bh[j], acc[i][j], 0,0,0);
        acc[i][j] = __builtin_amdgcn_mfma_f32_16x16x32_bf16(ah[i], bl[j], acc[i][j], 0,0,0);
        acc[i][j] = __builtin_amdgcn_mfma_f32_16x16x32_bf16(al[i], bh[j], acc[i][j], 0,0,0);
      }
  }

  const float bb = bS[0];
  float pj[4];
  #pragma unroll
  for (int j=0;j<4;++j){
    int col = bn + wn*64 + j*16 + lr;
    pj[j] = p[col < N_TOT ? col : N_TOT-1];
  }
  #pragma unroll
  for (int i=0;i<4;++i){
    #pragma unroll
    for (int rr=0;rr<4;++rr){
      int row = bm + wm*64 + i*16 + kq*4 + rr;
      if (row < N_TOT){
        float pi = p[row];
        #pragma unroll
        for (int j=0;j<4;++j){
          int col = bn + wn*64 + j*16 + lr;
          if (col < N_TOT)
            __builtin_nontemporal_store(
                fmaxf(pi + pj[j] + bb - 2.f*acc[i][j][rr], 0.f),
                scores + (size_t)row*N_TOT + col);
        }
      }
    }
  }
}

// ---------------- exact per-row top-50 + softmax -------------------------------
__global__ __launch_bounds__(256) void topk_kernel(const float* __restrict__ scores,
                                                   int* __restrict__ idxO,
                                                   float* __restrict__ softO){
  const int row = blockIdx.x, tid = threadIdx.x;
  const float4* srow = (const float4*)(scores + (size_t)row*N_TOT);
  float4 v[10];
  #pragma unroll
  for (int s=0;s<10;++s){
    int fi = tid + s*256;
    v[s] = (fi < 2500) ? srow[fi] : make_float4(-1.f,-1.f,-1.f,-1.f);
  }
  float mx = -1.f;
  #pragma unroll
  for (int s=0;s<10;++s)
    mx = fmaxf(mx, fmaxf(fmaxf(v[s].x,v[s].y), fmaxf(v[s].z,v[s].w)));
  __shared__ float redf[4];
  __shared__ int cntS;
  float wm = waveMaxF(mx);
  if ((tid&63)==0) redf[tid>>6] = wm;
  __syncthreads();
  mx = fmaxf(fmaxf(redf[0],redf[1]), fmaxf(redf[2],redf[3]));

  unsigned lo = 0, hi = __float_as_uint(mx);
  while (lo < hi){
    unsigned mid = (lo + hi) >> 1;
    float t = __uint_as_float(mid);
    int c = 0;
    #pragma unroll
    for (int s=0;s<10;++s)
      c += (v[s].x>t) + (v[s].y>t) + (v[s].z>t) + (v[s].w>t);
    if (tid==0) cntS = 0;
    __syncthreads();
    c = waveSumI(c);
    if ((tid&63)==0) atomicAdd(&cntS, c);
    __syncthreads();
    int total = cntS;
    __syncthreads();
    if (total >= TK) lo = mid + 1; else hi = mid;
  }
  const float v50 = __uint_as_float(lo);

  __shared__ int   selIdx[TK];
  __shared__ float selVal[TK];
  __shared__ int cSel, cTie;
  if (tid==0){ cSel=0; cTie=0; }
  __syncthreads();
  #pragma unroll
  for (int s=0;s<10;++s){
    int base = 4*(tid + s*256);
    float vals[4] = {v[s].x, v[s].y, v[s].z, v[s].w};
    #pragma unroll
    for (int e=0;e<4;++e){
      if (vals[e] > v50){ int q = atomicAdd(&cSel,1); selIdx[q]=base+e; selVal[q]=vals[e]; }
    }
  }
  __syncthreads();
  const int m = cSel;
  #pragma unroll
  for (int s=0;s<10;++s){
    int base = 4*(tid + s*256);
    float vals[4] = {v[s].x, v[s].y, v[s].z, v[s].w};
    #pragma unroll
    for (int e=0;e<4;++e){
      if (vals[e] == v50){
        int q = atomicAdd(&cTie,1);
        if (m + q < TK){ selIdx[m+q]=base+e; selVal[m+q]=v50; }
      }
    }
  }
  __syncthreads();
  if (tid < 64){
    float e = (tid < TK) ? __expf(selVal[tid] - mx) : 0.f;
    float s = waveSumF(e);
    if (tid < TK){
      softO[row*TK + tid] = e / s;
      idxO [row*TK + tid] = selIdx[tid];
    }
  }
}

// ---------------- scatter soft into dense S ------------------------------------
__global__ void scatter_kernel(const int* __restrict__ idx, const float* __restrict__ soft,
                               float* __restrict__ S){
  int t = blockIdx.x*blockDim.x + threadIdx.x;
  if (t < N_TOT*TK){
    int i = t / TK;
    S[(size_t)i*N_TOT + idx[t]] = soft[t];
  }
}

// ---------------- loss = sum(dp*soft) + gamma*sum(soft) ------------------------
__global__ __launch_bounds__(256) void loss_kernel(const float* __restrict__ feat,
                                                   const float* __restrict__ xn,
                                                   const int* __restrict__ idx,
                                                   const float* __restrict__ soft,
                                                   float* __restrict__ lossOut){
  int row = blockIdx.x;
  int grp = threadIdx.x>>6, lane = threadIdx.x&63;
  const float2 a = ((const float2*)(feat + (size_t)row*CDIM))[lane];
  float acc = 0.f;
  for (int k=grp; k<TK; k+=4){
    int   j = idx [row*TK + k];
    float s = soft[row*TK + k];
    const float2 b = ((const float2*)(feat + (size_t)j*CDIM))[lane];
    float d = a.x*b.x + a.y*b.y;
    d = waveSumF(d);
    if (lane==0){
      float dp = fmaxf(xn[row] + xn[j] - 2.f*d, 0.f);
      acc += s*dp + GAMMA_REG*s;
    }
  }
  __shared__ float part[4];
  if (lane==0) part[grp] = acc;
  __syncthreads();
  if (threadIdx.x==0) atomicAdd(lossOut, part[0]+part[1]+part[2]+part[3]);
}

// ---------------- h[i][c] = relu(b1[c] + sum_k soft * X1[idx_k][c]) ------------
__global__ __launch_bounds__(256) void h_kernel(const float* __restrict__ X1,
                                                const int* __restrict__ idx,
                                                const float* __restrict__ soft,
                                                const float* __restrict__ b1,
                                                float* __restrict__ h){
  int row = blockIdx.x, c = threadIdx.x;
  __shared__ int   ji[TK];
  __shared__ float sv[TK];
  if (c < TK){ ji[c]=idx[row*TK+c]; sv[c]=soft[row*TK+c]; }
  __syncthreads();
  float acc = b1[c];
  #pragma unroll 10
  for (int k=0;k<TK;++k) acc = fmaf(sv[k], X1[(size_t)ji[k]*NHID_ + c], acc);
  h[(size_t)row*NHID_ + c] = fmaxf(acc, 0.f);
}

// ---------------- X2 = h @ W2 (W2 in LDS) --------------------------------------
__global__ __launch_bounds__(256) void x2_kernel(const float* __restrict__ h,
                                                 const float* __restrict__ W2,
                                                 float* __restrict__ X2){
  __shared__ float w[NHID_*NCLS];
  for (int i=threadIdx.x; i<NHID_*NCLS; i+=256) w[i] = W2[i];
  __syncthreads();
  int t = blockIdx.x*256 + threadIdx.x;
  if (t < N_TOT*NCLS){
    int r = t / NCLS, c = t % NCLS;
    float acc = 0.f;
    const float* hr = h + (size_t)r*NHID_;
    #pragma unroll 8
    for (int k=0;k<NHID_;++k) acc = fmaf(hr[k], w[k*NCLS+c], acc);
    X2[t] = acc;
  }
}

// ------- logits[i][c] = b2[c] + sum_k soft*X2[idx_k][c]; semi = log_softmax ----
__global__ __launch_bounds__(64) void logits_kernel(const float* __restrict__ X2,
                                                    const int* __restrict__ idx,
                                                    const float* __restrict__ soft,
                                                    const float* __restrict__ b2,
                                                    float* __restrict__ semi){
  int row = blockIdx.x, tid = threadIdx.x;
  __shared__ int   ji[TK];
  __shared__ float sv[TK];
  if (tid < TK){ ji[tid]=idx[row*TK+tid]; sv[tid]=soft[row*TK+tid]; }
  __syncthreads();
  float acc = 0.f;
  if (tid < NCLS){
    acc = b2[tid];
    for (int k=0;k<TK;++k) acc = fmaf(sv[k], X2[(size_t)ji[k]*NCLS + tid], acc);
  }
  float mv = (tid < NCLS) ? acc : -1e30f;
  #pragma unroll
  for (int o=8;o;o>>=1) mv = fmaxf(mv, __shfl_xor(mv,o,16));
  float e = (tid < NCLS) ? __expf(acc - mv) : 0.f;
  #pragma unroll
  for (int o=8;o;o>>=1) e += __shfl_xor(e,o,16);
  if (tid < NCLS) semi[row*NCLS + tid] = acc - mv - logf(e);
}

extern "C" void kernel_launch(void* const* d_in, const int* in_sizes, int n_in,
                              void* d_out, int out_size, void* d_ws, size_t ws_size,
                              hipStream_t stream){
  const float* inputs   = (const float*)d_in[0];
  const float* W_lin    = (const float*)d_in[1];
  const float* b_lin    = (const float*)d_in[2];
  const float* bn_gamma = (const float*)d_in[3];
  const float* bn_beta  = (const float*)d_in[4];
  const float* a_S      = (const float*)d_in[5];
  const float* b_S      = (const float*)d_in[6];
  const float* W1       = (const float*)d_in[7];
  const float* b1       = (const float*)d_in[8];
  const float* W2       = (const float*)d_in[9];
  const float* b2       = (const float*)d_in[10];

  float* out  = (float*)d_out;
  float* ws   = (float*)d_ws;

  // ws layout (float offsets), total 7,520,000 floats = 30.1 MB
  float*  feat = ws;                        // [0        .. 1,280,000)
  float*  p    = ws + 1280000;              // [1,280,000.. 1,290,000)
  float*  xn   = ws + 1290000;              // [1,290,000.. 1,300,000)
  int*    idxb = (int*)(ws + 1300000);      // [1,300,000.. 1,800,000)
  float*  soft = ws + 1800000;              // [1,800,000.. 2,300,000)
  float*  X1   = ws + 2300000;              // [2,300,000.. 4,860,000)
  // bf16 split buffers: each 1,280,000 ushorts = 640,000 floats.
  // Dead after score_mfma; hbuf reuses the region at step 10.
  ushort* fh   = (ushort*)(ws + 4860000);
  ushort* fl   = (ushort*)(ws + 5500000);
  ushort* gh   = (ushort*)(ws + 6140000);
  ushort* gl   = (ushort*)(ws + 6780000);
  float*  hbuf = ws + 4860000;              // reuse of split region (after score)
  float*  X2   = ws + 7420000;              // [7,420,000.. 7,520,000)

  float* semi    = out;
  float* lossOut = out + 100000;
  float* Sout    = out + 100001;
  float* scratch = out + 100000;            // score scratch (overwritten later)

  // 1. lin = inputs @ W_lin + b_lin
  gemm64<true><<<dim3(2,157), 256, 0, stream>>>(inputs, W_lin, b_lin, feat, N_TOT, CDIM, 3072);
  // 2. per-chunk BN in place
  bn_kernel<<<100, CDIM, 0, stream>>>(feat, bn_gamma, bn_beta);
  // 3. bf16 splits + p, xn
  featsplit<<<2500, 256, 0, stream>>>(feat, a_S, fh, fl, gh, gl, p, xn);
  // 4. scores via LDS-staged split-bf16 MFMA -> scratch (128 KiB dynamic LDS)
  score_mfma<<<6241, 256, 131072, stream>>>(fh, fl, gh, gl, p, b_S, scratch);
  // 5. X1 = feat @ W1
  gemm64<false><<<dim3(4,157), 256, 0, stream>>>(feat, W1, nullptr, X1, N_TOT, NHID_, CDIM);
  // 6. exact top-50 + softmax
  topk_kernel<<<N_TOT, 256, 0, stream>>>(scratch, idxb, soft);
  // 7. zero loss + S (after topk has consumed scratch)
  hipMemsetAsync(lossOut, 0, (size_t)100000001*sizeof(float), stream);
  // 8. scatter S
  scatter_kernel<<<(N_TOT*TK+255)/256, 256, 0, stream>>>(idxb, soft, Sout);
  // 9. loss
  loss_kernel<<<N_TOT, 256, 0, stream>>>(feat, xn, idxb, soft, lossOut);
  // 10. h = relu(S@X1 + b1)  (hbuf overwrites dead split buffers)
  h_kernel<<<N_TOT, NHID_, 0, stream>>>(X1, idxb, soft, b1, hbuf);
  // 11. X2 = h @ W2
  x2_kernel<<<(N_TOT*NCLS+255)/256, 256, 0, stream>>>(hbuf, W2, X2);
  // 12. logits + log_softmax
  logits_kernel<<<N_TOT, 64, 0, stream>>>(X2, idxb, soft, b2, semi);
}

// Round 6
// 1155.948 us; speedup vs baseline: 1.2763x; 1.2763x over previous
//
#include <hip/hip_runtime.h>
#include <hip/hip_bf16.h>
#include <cstdint>
#include <cstddef>

#define N_TOT 10000
#define CDIM  128
#define TK    50
#define NHID_ 256
#define NCLS  10
#define GAMMA_REG 0.01f
#define BN_EPS 1e-5f

typedef float f32x4 __attribute__((ext_vector_type(4)));
typedef short s16x8 __attribute__((ext_vector_type(8)));

__device__ __forceinline__ float waveSumF(float v){
  #pragma unroll
  for (int o=32;o;o>>=1) v += __shfl_xor(v,o,64);
  return v;
}
__device__ __forceinline__ float waveMaxF(float v){
  #pragma unroll
  for (int o=32;o;o>>=1) v = fmaxf(v,__shfl_xor(v,o,64));
  return v;
}
__device__ __forceinline__ int waveSumI(int v){
  #pragma unroll
  for (int o=32;o;o>>=1) v += __shfl_xor(v,o,64);
  return v;
}
__device__ __forceinline__ ushort bfh(float f){
  __hip_bfloat16 h = __float2bfloat16(f);          // RNE
  return *reinterpret_cast<ushort*>(&h);
}
__device__ __forceinline__ float bf2f(ushort u){
  __hip_bfloat16 h = *reinterpret_cast<__hip_bfloat16*>(&u);
  return __bfloat162float(h);
}
__device__ __forceinline__ void gload16(const void* g, void* l){
  __builtin_amdgcn_global_load_lds(
      (const __attribute__((address_space(1))) void*)g,
      (__attribute__((address_space(3))) void*)l, 16, 0, 0);
}

// ---------------- generic 64x64 fp32 GEMM (used only for X1 = feat @ W1) -------
template<bool BIAS>
__global__ __launch_bounds__(256) void gemm64(const float* __restrict__ A,
                                              const float* __restrict__ B,
                                              const float* __restrict__ bias,
                                              float* __restrict__ C,
                                              int M, int N, int K){
  constexpr int BK=32;
  __shared__ float As[BK][64+4];
  __shared__ float Bs[BK][64+4];
  const int tid = threadIdx.x;
  const int bm = blockIdx.y*64, bn = blockIdx.x*64;
  const int tm = (tid>>4)<<2;
  const int tn = (tid&15)<<2;
  float acc[4][4] = {};
  for (int k0=0;k0<K;k0+=BK){
    #pragma unroll
    for (int i=0;i<2;++i){
      int fi = tid + i*256;
      int r  = fi>>3;
      int c4 = fi&7;
      float4 v = make_float4(0,0,0,0);
      int gr = bm + r;
      if (gr < M) v = *(const float4*)(A + (size_t)gr*K + k0 + (c4<<2));
      As[(c4<<2)+0][r]=v.x; As[(c4<<2)+1][r]=v.y; As[(c4<<2)+2][r]=v.z; As[(c4<<2)+3][r]=v.w;
    }
    #pragma unroll
    for (int i=0;i<2;++i){
      int fi = tid + i*256;
      int r  = fi>>4;
      int c4 = fi&15;
      float4 v = *(const float4*)(B + (size_t)(k0+r)*N + bn + (c4<<2));
      *(float4*)&Bs[r][c4<<2] = v;
    }
    __syncthreads();
    #pragma unroll
    for (int kk=0;kk<BK;++kk){
      float a[4], b[4];
      *(float4*)a = *(const float4*)&As[kk][tm];
      *(float4*)b = *(const float4*)&Bs[kk][tn];
      #pragma unroll
      for (int i=0;i<4;++i)
        #pragma unroll
        for (int j=0;j<4;++j) acc[i][j] = fmaf(a[i], b[j], acc[i][j]);
    }
    __syncthreads();
  }
  #pragma unroll
  for (int i=0;i<4;++i){
    int gr = bm+tm+i;
    if (gr < M){
      float4 o; o.x=acc[i][0]; o.y=acc[i][1]; o.z=acc[i][2]; o.w=acc[i][3];
      if (BIAS){
        o.x += bias[bn+tn+0]; o.y += bias[bn+tn+1];
        o.z += bias[bn+tn+2]; o.w += bias[bn+tn+3];
      }
      *(float4*)(C + (size_t)gr*N + bn + tn) = o;
    }
  }
}

// ---- W transpose + split: W[3072][128] -> Wth/Wtl[128][3072] bf16 hi/lo -------
__global__ __launch_bounds__(256) void wtprep(const float* __restrict__ W,
                                              ushort* __restrict__ Wth,
                                              ushort* __restrict__ Wtl){
  __shared__ float t[64][129];
  const int tid = threadIdx.x;
  const int kb = blockIdx.x*64;
  #pragma unroll
  for (int it=0; it<8; ++it){
    int cs = it*256 + tid;            // [0,2048)
    int kr = cs >> 5;                 // 32 float4 per 128-col row
    int c4 = cs & 31;
    float4 v = *(const float4*)(W + (size_t)(kb+kr)*128 + c4*4);
    t[kr][c4*4+0]=v.x; t[kr][c4*4+1]=v.y; t[kr][c4*4+2]=v.z; t[kr][c4*4+3]=v.w;
  }
  __syncthreads();
  #pragma unroll
  for (int it=0; it<4; ++it){
    int ch = it*256 + tid;            // [0,1024)
    int n  = ch >> 3;
    int k8 = (ch & 7)*8;
    s16x8 hv, lv;
    #pragma unroll
    for (int e=0;e<8;++e){
      float v = t[k8+e][n];
      ushort h = bfh(v);
      hv[e] = (short)h;
      lv[e] = (short)bfh(v - bf2f(h));
    }
    *(s16x8*)(Wth + (size_t)n*3072 + kb + k8) = hv;
    *(s16x8*)(Wtl + (size_t)n*3072 + kb + k8) = lv;
  }
}

// ---- lin partials: P[kc][m][n] = inputs[m, kc*384:(kc+1)*384] @ W[.., n] ------
// split-bf16 3-product MFMA; A reg-staged fp32->bf16 LDS, Wt gload16-staged.
__global__ __launch_bounds__(256,2) void lin_mfma(const float* __restrict__ Ain,
                                                  const ushort* __restrict__ Wth,
                                                  const ushort* __restrict__ Wtl,
                                                  float* __restrict__ P){
  extern __shared__ char lds[];          // 64 KiB: Ah@0 Al@16K Bh@32K Bl@48K
  ushort* ldsu = (ushort*)lds;
  const int tid = threadIdx.x, lane = tid&63, wave = tid>>6;
  const int wm = wave>>1, wn = wave&1;
  const int mt = blockIdx.x % 79, kc = blockIdx.x / 79;
  const int bm = mt*128;
  const int lr = lane&15, kq = lane>>4;
  f32x4 acc[4][4] = {};

  for (int st=0; st<6; ++st){
    const int kb = kc*384 + st*64;
    if (st) __syncthreads();
    // A: fp32 -> split bf16, swizzled ds_write
    #pragma unroll
    for (int it=0; it<8; ++it){
      int cs = it*256+tid, row = cs>>4, c4 = cs&15;
      int rg = bm+row; rg = rg < N_TOT ? rg : N_TOT-1;
      float4 v = *(const float4*)(Ain + (size_t)rg*3072 + kb + c4*4);
      ushort4 h, l;
      h.x=bfh(v.x); l.x=bfh(v.x-bf2f(h.x));
      h.y=bfh(v.y); l.y=bfh(v.y-bf2f(h.y));
      h.z=bfh(v.z); l.z=bfh(v.z-bf2f(h.z));
      h.w=bfh(v.w); l.w=bfh(v.w-bf2f(h.w));
      int bo = (c4*8) ^ ((row&7)<<4);
      *(ushort4*)(lds + row*128 + bo)         = h;
      *(ushort4*)(lds + 16384 + row*128 + bo) = l;
    }
    // Wt: bf16 direct DMA, inverse-swizzled source
    #pragma unroll
    for (int it=0; it<4; ++it){
      int cs = it*256+tid, row = cs>>3, slot = cs&7;
      int srcb = (slot*16) ^ ((row&7)<<4);
      gload16(Wth + (size_t)row*3072 + kb + (srcb>>1), ldsu + 16384 + cs*8);
      gload16(Wtl + (size_t)row*3072 + kb + (srcb>>1), ldsu + 24576 + cs*8);
    }
    __syncthreads();
    #pragma unroll
    for (int ks=0; ks<2; ++ks){
      const int kbyte = ks*64 + kq*16;
      s16x8 yh[4], yl[4];
      #pragma unroll
      for (int j=0;j<4;++j){
        int ma = wm*64 + j*16 + lr;
        int oa = ma*128 + (kbyte ^ ((ma&7)<<4));
        yh[j] = *(const s16x8*)(lds + oa);
        yl[j] = *(const s16x8*)(lds + 16384 + oa);
      }
      #pragma unroll
      for (int i=0;i<4;++i){
        int na = wn*64 + i*16 + lr;
        int ob = na*128 + (kbyte ^ ((na&7)<<4));
        s16x8 xh = *(const s16x8*)(lds + 32768 + ob);
        s16x8 xl = *(const s16x8*)(lds + 49152 + ob);
        #pragma unroll
        for (int j=0;j<4;++j){
          acc[i][j] = __builtin_amdgcn_mfma_f32_16x16x32_bf16(xh, yh[j], acc[i][j],0,0,0);
          acc[i][j] = __builtin_amdgcn_mfma_f32_16x16x32_bf16(xh, yl[j], acc[i][j],0,0,0);
          acc[i][j] = __builtin_amdgcn_mfma_f32_16x16x32_bf16(xl, yh[j], acc[i][j],0,0,0);
        }
      }
    }
  }
  // acc[i][j]: n = wn*64+i*16+kq*4+reg (Wt rows), m = bm+wm*64+j*16+lr (A rows)
  #pragma unroll
  for (int j=0;j<4;++j){
    int m = bm + wm*64 + j*16 + lr;
    if (m < N_TOT){
      float* Pr = P + ((size_t)kc*N_TOT + m)*CDIM;
      #pragma unroll
      for (int i=0;i<4;++i)
        *(f32x4*)(Pr + wn*64 + i*16 + kq*4) = acc[i][j];
    }
  }
}

// ---- feat = bias + sum_kc P[kc] -----------------------------------------------
__global__ __launch_bounds__(256) void lin_reduce(const float* __restrict__ P,
                                                  const float* __restrict__ bias,
                                                  float* __restrict__ feat){
  int e = blockIdx.x*256 + threadIdx.x;      // 1,280,000 total
  float s = bias[e & 127];
  #pragma unroll
  for (int kc=0;kc<8;++kc) s += P[(size_t)kc*1280000 + e];
  feat[e] = s;
}

// ---------------- per-chunk BatchNorm (training stats, biased var), in place ----
__global__ __launch_bounds__(512) void bn_kernel(float* __restrict__ feat,
                                                 const float* __restrict__ g,
                                                 const float* __restrict__ b){
  int chunk = blockIdx.x;
  int c = threadIdx.x & 127, rq = threadIdx.x >> 7;
  __shared__ float S1[4][128], S2[4][128];
  float* base = feat + (size_t)chunk*100*CDIM;
  float s=0.f, s2=0.f;
  for (int r=rq*25; r<rq*25+25; ++r){ float v = base[r*CDIM+c]; s+=v; s2+=v*v; }
  S1[rq][c]=s; S2[rq][c]=s2;
  __syncthreads();
  if (rq==0){
    float ts = S1[0][c]+S1[1][c]+S1[2][c]+S1[3][c];
    float t2 = S2[0][c]+S2[1][c]+S2[2][c]+S2[3][c];
    float mu = ts*0.01f;
    float var = t2*0.01f - mu*mu;
    float sc = g[c]*rsqrtf(var+BN_EPS);
    S1[0][c] = sc; S2[0][c] = b[c] - mu*sc;
  }
  __syncthreads();
  float sc = S1[0][c], sh = S2[0][c];
  for (int r=rq*25; r<rq*25+25; ++r) base[r*CDIM+c] = base[r*CDIM+c]*sc + sh;
}

// ------- split feat into bf16 hi/lo (plain: fh/fl, a-scaled: gh/gl) + p, xn ----
__global__ __launch_bounds__(256) void featsplit(const float* __restrict__ feat,
                                                 const float* __restrict__ aS,
                                                 ushort* __restrict__ fh, ushort* __restrict__ fl,
                                                 ushort* __restrict__ gh, ushort* __restrict__ gl,
                                                 float* __restrict__ p, float* __restrict__ xn){
  int wave = threadIdx.x>>6, lane = threadIdx.x&63;
  int row = blockIdx.x*4 + wave;
  const float2 f = ((const float2*)(feat + (size_t)row*CDIM))[lane];
  const float2 a = ((const float2*)aS)[lane];
  float gx = f.x*a.x, gy = f.y*a.y;

  ushort2 v;
  size_t o = (size_t)row*64 + lane;
  v.x = bfh(f.x); v.y = bfh(f.y);
  ((ushort2*)fh)[o] = v;
  ushort2 vl; vl.x = bfh(f.x - bf2f(v.x)); vl.y = bfh(f.y - bf2f(v.y));
  ((ushort2*)fl)[o] = vl;
  ushort2 w; w.x = bfh(gx); w.y = bfh(gy);
  ((ushort2*)gh)[o] = w;
  ushort2 wl2; wl2.x = bfh(gx - bf2f(w.x)); wl2.y = bfh(gy - bf2f(w.y));
  ((ushort2*)gl)[o] = wl2;

  float sp = gx*f.x + gy*f.y;
  float sx = f.x*f.x + f.y*f.y;
  sp = waveSumF(sp); sx = waveSumF(sx);
  if (lane==0){ p[row]=sp; xn[row]=sx; }
}

// -------- scores[i][j] = relu(p_i + p_j + b - 2*(g_i . f_j)), split-bf16 MFMA --
// BK=64 two-phase staging, 64 KiB LDS (2 blocks/CU), XOR swizzle both sides.
__global__ __launch_bounds__(256,2) void score_mfma(const ushort* __restrict__ fh,
                                                    const ushort* __restrict__ fl,
                                                    const ushort* __restrict__ gh,
                                                    const ushort* __restrict__ gl,
                                                    const float* __restrict__ p,
                                                    const float* __restrict__ bS,
                                                    float* __restrict__ scores){
  extern __shared__ char lds[];        // 64 KiB: Gh@0 Gl@16K Fh@32K Fl@48K
  ushort* ldsu = (ushort*)lds;
  const int tid  = threadIdx.x;
  const int lane = tid & 63;
  const int wave = tid >> 6;
  const int wm = wave >> 1, wn = wave & 1;

  // bijective XCD-chunk swizzle (m204): nwg=6241, 8 XCDs; col-major tile map
  const int nwg = 6241, q = nwg >> 3, r = nwg & 7;   // q=780, r=1
  int bid = blockIdx.x;
  int xcd = bid & 7, loc = bid >> 3;
  int wid = (xcd < r ? xcd*(q+1) : r*(q+1) + (xcd-r)*q) + loc;
  const int bxt = wid / 79;
  const int byt = wid % 79;
  const int bm = byt*128;
  const int bn = bxt*128;
  const int lr = lane & 15;
  const int kq = lane >> 4;
  f32x4 acc[4][4] = {};

  for (int ko=0; ko<2; ++ko){
    const int k0 = ko*64;
    if (ko) __syncthreads();
    #define STG(SRC, RB, UOFF)                                                  \
      { _Pragma("unroll")                                                       \
        for (int it=0; it<4; ++it){                                             \
          int cs = it*256 + tid;                                                \
          int row = cs >> 3;                                                    \
          int srcb = ((cs & 7) << 4) ^ ((row & 7) << 4);                        \
          int rg = (RB) + row; rg = (rg < N_TOT ? rg : N_TOT-1);                \
          gload16(SRC + (size_t)rg*CDIM + k0 + (srcb >> 1),                     \
                  ldsu + (UOFF) + cs*8);                                        \
        } }
    STG(gh, bm, 0)
    STG(gl, bm, 8192)
    STG(fh, bn, 16384)
    STG(fl, bn, 24576)
    #undef STG
    __syncthreads();

    #pragma unroll
    for (int ks=0; ks<2; ++ks){
      const int kbyte = ks*64 + kq*16;
      s16x8 yh[4], yl[4];                      // f (column) fragments, resident
      #pragma unroll
      for (int j=0;j<4;++j){
        int ca = wn*64 + j*16 + lr;
        int ob = ca*128 + (kbyte ^ ((ca&7)<<4));
        yh[j] = *(const s16x8*)(lds + 32768 + ob);
        yl[j] = *(const s16x8*)(lds + 49152 + ob);
      }
      #pragma unroll
      for (int i=0;i<4;++i){                   // g (row) fragments, streamed
        int ra = wm*64 + i*16 + lr;
        int oa = ra*128 + (kbyte ^ ((ra&7)<<4));
        s16x8 xh = *(const s16x8*)(lds + oa);
        s16x8 xl = *(const s16x8*)(lds + 16384 + oa);
        #pragma unroll
        for (int j=0;j<4;++j){
          acc[i][j] = __builtin_amdgcn_mfma_f32_16x16x32_bf16(xh, yh[j], acc[i][j],0,0,0);
          acc[i][j] = __builtin_amdgcn_mfma_f32_16x16x32_bf16(xh, yl[j], acc[i][j],0,0,0);
          acc[i][j] = __builtin_amdgcn_mfma_f32_16x16x32_bf16(xl, yh[j], acc[i][j],0,0,0);
        }
      }
    }
  }

  const float bb = bS[0];
  float pj[4];
  #pragma unroll
  for (int j=0;j<4;++j){
    int col = bn + wn*64 + j*16 + lr;
    pj[j] = p[col < N_TOT ? col : N_TOT-1];
  }
  #pragma unroll
  for (int i=0;i<4;++i){
    #pragma unroll
    for (int rr=0;rr<4;++rr){
      int row = bm + wm*64 + i*16 + kq*4 + rr;
      if (row < N_TOT){
        float pi = p[row];
        #pragma unroll
        for (int j=0;j<4;++j){
          int col = bn + wn*64 + j*16 + lr;
          if (col < N_TOT)
            scores[(size_t)row*N_TOT + col] = fmaxf(pi + pj[j] + bb - 2.f*acc[i][j][rr], 0.f);
        }
      }
    }
  }
}

// ---------------- exact per-row top-50 + softmax -------------------------------
__global__ __launch_bounds__(256) void topk_kernel(const float* __restrict__ scores,
                                                   int* __restrict__ idxO,
                                                   float* __restrict__ softO){
  const int row = blockIdx.x, tid = threadIdx.x;
  const float4* srow = (const float4*)(scores + (size_t)row*N_TOT);
  float4 v[10];
  #pragma unroll
  for (int s=0;s<10;++s){
    int fi = tid + s*256;
    v[s] = (fi < 2500) ? srow[fi] : make_float4(-1.f,-1.f,-1.f,-1.f);
  }
  float mx = -1.f;
  #pragma unroll
  for (int s=0;s<10;++s)
    mx = fmaxf(mx, fmaxf(fmaxf(v[s].x,v[s].y), fmaxf(v[s].z,v[s].w)));
  __shared__ float redf[4];
  __shared__ int cntS;
  float wm = waveMaxF(mx);
  if ((tid&63)==0) redf[tid>>6] = wm;
  __syncthreads();
  mx = fmaxf(fmaxf(redf[0],redf[1]), fmaxf(redf[2],redf[3]));

  unsigned lo = 0, hi = __float_as_uint(mx);
  while (lo < hi){
    unsigned mid = (lo + hi) >> 1;
    float t = __uint_as_float(mid);
    int c = 0;
    #pragma unroll
    for (int s=0;s<10;++s)
      c += (v[s].x>t) + (v[s].y>t) + (v[s].z>t) + (v[s].w>t);
    if (tid==0) cntS = 0;
    __syncthreads();
    c = waveSumI(c);
    if ((tid&63)==0) atomicAdd(&cntS, c);
    __syncthreads();
    int total = cntS;
    __syncthreads();
    if (total >= TK) lo = mid + 1; else hi = mid;
  }
  const float v50 = __uint_as_float(lo);

  __shared__ int   selIdx[TK];
  __shared__ float selVal[TK];
  __shared__ int cSel, cTie;
  if (tid==0){ cSel=0; cTie=0; }
  __syncthreads();
  #pragma unroll
  for (int s=0;s<10;++s){
    int base = 4*(tid + s*256);
    float vals[4] = {v[s].x, v[s].y, v[s].z, v[s].w};
    #pragma unroll
    for (int e=0;e<4;++e){
      if (vals[e] > v50){ int q = atomicAdd(&cSel,1); selIdx[q]=base+e; selVal[q]=vals[e]; }
    }
  }
  __syncthreads();
  const int m = cSel;
  #pragma unroll
  for (int s=0;s<10;++s){
    int base = 4*(tid + s*256);
    float vals[4] = {v[s].x, v[s].y, v[s].z, v[s].w};
    #pragma unroll
    for (int e=0;e<4;++e){
      if (vals[e] == v50){
        int q = atomicAdd(&cTie,1);
        if (m + q < TK){ selIdx[m+q]=base+e; selVal[m+q]=v50; }
      }
    }
  }
  __syncthreads();
  if (tid < 64){
    float e = (tid < TK) ? __expf(selVal[tid] - mx) : 0.f;
    float s = waveSumF(e);
    if (tid < TK){
      softO[row*TK + tid] = e / s;
      idxO [row*TK + tid] = selIdx[tid];
    }
  }
}

// ---------------- scatter soft into dense S ------------------------------------
__global__ void scatter_kernel(const int* __restrict__ idx, const float* __restrict__ soft,
                               float* __restrict__ S){
  int t = blockIdx.x*blockDim.x + threadIdx.x;
  if (t < N_TOT*TK){
    int i = t / TK;
    S[(size_t)i*N_TOT + idx[t]] = soft[t];
  }
}

// ---------------- loss = sum(dp*soft) + gamma*sum(soft) (into 256 slots) -------
__global__ __launch_bounds__(256) void loss_kernel(const float* __restrict__ feat,
                                                   const float* __restrict__ xn,
                                                   const int* __restrict__ idx,
                                                   const float* __restrict__ soft,
                                                   float* __restrict__ slots){
  int row = blockIdx.x;
  int grp = threadIdx.x>>6, lane = threadIdx.x&63;
  const float2 a = ((const float2*)(feat + (size_t)row*CDIM))[lane];
  float acc = 0.f;
  for (int k=grp; k<TK; k+=4){
    int   j = idx [row*TK + k];
    float s = soft[row*TK + k];
    const float2 b = ((const float2*)(feat + (size_t)j*CDIM))[lane];
    float d = a.x*b.x + a.y*b.y;
    d = waveSumF(d);
    if (lane==0){
      float dp = fmaxf(xn[row] + xn[j] - 2.f*d, 0.f);
      acc += s*dp + GAMMA_REG*s;
    }
  }
  __shared__ float part[4];
  if (lane==0) part[grp] = acc;
  __syncthreads();
  if (threadIdx.x==0) atomicAdd(&slots[row & 255], part[0]+part[1]+part[2]+part[3]);
}

__global__ void loss_finish(const float* __restrict__ slots, float* __restrict__ lossOut){
  float v = slots[threadIdx.x];
  v = waveSumF(v);
  __shared__ float pp[4];
  if ((threadIdx.x&63)==0) pp[threadIdx.x>>6] = v;
  __syncthreads();
  if (threadIdx.x==0) lossOut[0] = pp[0]+pp[1]+pp[2]+pp[3];
}

// ---------------- h[i][c] = relu(b1[c] + sum_k soft * X1[idx_k][c]) ------------
__global__ __launch_bounds__(256) void h_kernel(const float* __restrict__ X1,
                                                const int* __restrict__ idx,
                                                const float* __restrict__ soft,
                                                const float* __restrict__ b1,
                                                float* __restrict__ h){
  int row = blockIdx.x, c = threadIdx.x;
  __shared__ int   ji[TK];
  __shared__ float sv[TK];
  if (c < TK){ ji[c]=idx[row*TK+c]; sv[c]=soft[row*TK+c]; }
  __syncthreads();
  float acc = b1[c];
  #pragma unroll 10
  for (int k=0;k<TK;++k) acc = fmaf(sv[k], X1[(size_t)ji[k]*NHID_ + c], acc);
  h[(size_t)row*NHID_ + c] = fmaxf(acc, 0.f);
}

// ---------------- X2 = h @ W2 (W2 in LDS) --------------------------------------
__global__ __launch_bounds__(256) void x2_kernel(const float* __restrict__ h,
                                                 const float* __restrict__ W2,
                                                 float* __restrict__ X2){
  __shared__ float w[NHID_*NCLS];
  for (int i=threadIdx.x; i<NHID_*NCLS; i+=256) w[i] = W2[i];
  __syncthreads();
  int t = blockIdx.x*256 + threadIdx.x;
  if (t < N_TOT*NCLS){
    int r = t / NCLS, c = t % NCLS;
    float acc = 0.f;
    const float* hr = h + (size_t)r*NHID_;
    #pragma unroll 8
    for (int k=0;k<NHID_;++k) acc = fmaf(hr[k], w[k*NCLS+c], acc);
    X2[t] = acc;
  }
}

// ------- logits[i][c] = b2[c] + sum_k soft*X2[idx_k][c]; semi = log_softmax ----
__global__ __launch_bounds__(64) void logits_kernel(const float* __restrict__ X2,
                                                    const int* __restrict__ idx,
                                                    const float* __restrict__ soft,
                                                    const float* __restrict__ b2,
                                                    float* __restrict__ semi){
  int row = blockIdx.x, tid = threadIdx.x;
  __shared__ int   ji[TK];
  __shared__ float sv[TK];
  if (tid < TK){ ji[tid]=idx[row*TK+tid]; sv[tid]=soft[row*TK+tid]; }
  __syncthreads();
  float acc = 0.f;
  if (tid < NCLS){
    acc = b2[tid];
    for (int k=0;k<TK;++k) acc = fmaf(sv[k], X2[(size_t)ji[k]*NCLS + tid], acc);
  }
  float mv = (tid < NCLS) ? acc : -1e30f;
  #pragma unroll
  for (int o=8;o;o>>=1) mv = fmaxf(mv, __shfl_xor(mv,o,16));
  float e = (tid < NCLS) ? __expf(acc - mv) : 0.f;
  #pragma unroll
  for (int o=8;o;o>>=1) e += __shfl_xor(e,o,16);
  if (tid < NCLS) semi[row*NCLS + tid] = acc - mv - logf(e);
}

extern "C" void kernel_launch(void* const* d_in, const int* in_sizes, int n_in,
                              void* d_out, int out_size, void* d_ws, size_t ws_size,
                              hipStream_t stream){
  const float* inputs   = (const float*)d_in[0];
  const float* W_lin    = (const float*)d_in[1];
  const float* b_lin    = (const float*)d_in[2];
  const float* bn_gamma = (const float*)d_in[3];
  const float* bn_beta  = (const float*)d_in[4];
  const float* a_S      = (const float*)d_in[5];
  const float* b_S      = (const float*)d_in[6];
  const float* W1       = (const float*)d_in[7];
  const float* b1       = (const float*)d_in[8];
  const float* W2       = (const float*)d_in[9];
  const float* b2       = (const float*)d_in[10];

  float* out  = (float*)d_out;
  float* ws   = (float*)d_ws;

  // ws layout (float offsets), total 7,520,256 floats ~= 30.1 MB
  float*  feat = ws;                        // [0        .. 1,280,000)
  float*  p    = ws + 1280000;
  float*  xn   = ws + 1290000;
  int*    idxb = (int*)(ws + 1300000);      // 500,000
  float*  soft = ws + 1800000;              // 500,000
  float*  X1   = ws + 2300000;              // 2,560,000
  ushort* fh   = (ushort*)(ws + 4860000);   // 640,000 f each
  ushort* fl   = (ushort*)(ws + 5500000);
  ushort* gh   = (ushort*)(ws + 6140000);
  ushort* gl   = (ushort*)(ws + 6780000);
  float*  hbuf = ws + 4860000;              // reuse of split region (after score)
  float*  X2   = ws + 7420000;              // 100,000
  float*  lossSlots = ws + 7520000;         // 256

  // d_out layout: semi[100000], loss[1], S[1e8]
  float* semi    = out;
  float* lossOut = out + 100000;
  float* Sout    = out + 100001;
  float* scratch = out + 100000;            // score scratch (overwritten later)

  // lin-phase scratch inside the (not-yet-used) S region, 16B-aligned
  const size_t SC = 100004;
  ushort* Wth  = (ushort*)(out + SC);                 // 393,216 ushorts
  ushort* Wtl  = (ushort*)(out + SC + 196608);
  float*  Part = out + SC + 393216;                   // 8 x 1,280,000 floats

  // 1. W transpose+split; lin partials via split-bf16 MFMA; reduce + bias
  wtprep<<<48, 256, 0, stream>>>(W_lin, Wth, Wtl);
  lin_mfma<<<632, 256, 65536, stream>>>(inputs, Wth, Wtl, Part);
  lin_reduce<<<5000, 256, 0, stream>>>(Part, b_lin, feat);
  // 2. per-chunk BN in place
  bn_kernel<<<100, 512, 0, stream>>>(feat, bn_gamma, bn_beta);
  // 3. bf16 splits + p, xn
  featsplit<<<2500, 256, 0, stream>>>(feat, a_S, fh, fl, gh, gl, p, xn);
  // 4. scores via two-phase LDS-staged split-bf16 MFMA -> scratch
  score_mfma<<<6241, 256, 65536, stream>>>(fh, fl, gh, gl, p, b_S, scratch);
  // 5. X1 = feat @ W1
  gemm64<false><<<dim3(4,157), 256, 0, stream>>>(feat, W1, nullptr, X1, N_TOT, NHID_, CDIM);
  // 6. exact top-50 + softmax
  topk_kernel<<<N_TOT, 256, 0, stream>>>(scratch, idxb, soft);
  // 7. zero loss + S (after topk consumed scratch) + loss slots
  hipMemsetAsync(lossOut, 0, (size_t)100000001*sizeof(float), stream);
  hipMemsetAsync(lossSlots, 0, 256*sizeof(float), stream);
  // 8. scatter S
  scatter_kernel<<<(N_TOT*TK+255)/256, 256, 0, stream>>>(idxb, soft, Sout);
  // 9. loss
  loss_kernel<<<N_TOT, 256, 0, stream>>>(feat, xn, idxb, soft, lossSlots);
  loss_finish<<<1, 256, 0, stream>>>(lossSlots, lossOut);
  // 10. h = relu(S@X1 + b1)  (hbuf overwrites dead split buffers)
  h_kernel<<<N_TOT, NHID_, 0, stream>>>(X1, idxb, soft, b1, hbuf);
  // 11. X2 = h @ W2
  x2_kernel<<<(N_TOT*NCLS+255)/256, 256, 0, stream>>>(hbuf, W2, X2);
  // 12. logits + log_softmax
  logits_kernel<<<N_TOT, 64, 0, stream>>>(X2, idxb, soft, b2, semi);
}

// Round 7
// 1095.698 us; speedup vs baseline: 1.3465x; 1.0550x over previous
//
#include <hip/hip_runtime.h>
#include <hip/hip_bf16.h>
#include <cstdint>
#include <cstddef>

#define N_TOT 10000
#define CDIM  128
#define TK    50
#define NHID_ 256
#define NCLS  10
#define GAMMA_REG 0.01f
#define BN_EPS 1e-5f

typedef float f32x4 __attribute__((ext_vector_type(4)));
typedef short s16x8 __attribute__((ext_vector_type(8)));

__device__ __forceinline__ float waveSumF(float v){
  #pragma unroll
  for (int o=32;o;o>>=1) v += __shfl_xor(v,o,64);
  return v;
}
__device__ __forceinline__ float waveMaxF(float v){
  #pragma unroll
  for (int o=32;o;o>>=1) v = fmaxf(v,__shfl_xor(v,o,64));
  return v;
}
__device__ __forceinline__ int waveSumI(int v){
  #pragma unroll
  for (int o=32;o;o>>=1) v += __shfl_xor(v,o,64);
  return v;
}
__device__ __forceinline__ ushort bfh(float f){
  __hip_bfloat16 h = __float2bfloat16(f);          // RNE
  return *reinterpret_cast<ushort*>(&h);
}
__device__ __forceinline__ float bf2f(ushort u){
  __hip_bfloat16 h = *reinterpret_cast<__hip_bfloat16*>(&u);
  return __bfloat162float(h);
}
__device__ __forceinline__ void gload16(const void* g, void* l){
  __builtin_amdgcn_global_load_lds(
      (const __attribute__((address_space(1))) void*)g,
      (__attribute__((address_space(3))) void*)l, 16, 0, 0);
}

// ---------------- generic 64x64 fp32 GEMM (used only for X1 = feat @ W1) -------
template<bool BIAS>
__global__ __launch_bounds__(256) void gemm64(const float* __restrict__ A,
                                              const float* __restrict__ B,
                                              const float* __restrict__ bias,
                                              float* __restrict__ C,
                                              int M, int N, int K){
  constexpr int BK=32;
  __shared__ float As[BK][64+4];
  __shared__ float Bs[BK][64+4];
  const int tid = threadIdx.x;
  const int bm = blockIdx.y*64, bn = blockIdx.x*64;
  const int tm = (tid>>4)<<2;
  const int tn = (tid&15)<<2;
  float acc[4][4] = {};
  for (int k0=0;k0<K;k0+=BK){
    #pragma unroll
    for (int i=0;i<2;++i){
      int fi = tid + i*256;
      int r  = fi>>3;
      int c4 = fi&7;
      float4 v = make_float4(0,0,0,0);
      int gr = bm + r;
      if (gr < M) v = *(const float4*)(A + (size_t)gr*K + k0 + (c4<<2));
      As[(c4<<2)+0][r]=v.x; As[(c4<<2)+1][r]=v.y; As[(c4<<2)+2][r]=v.z; As[(c4<<2)+3][r]=v.w;
    }
    #pragma unroll
    for (int i=0;i<2;++i){
      int fi = tid + i*256;
      int r  = fi>>4;
      int c4 = fi&15;
      float4 v = *(const float4*)(B + (size_t)(k0+r)*N + bn + (c4<<2));
      *(float4*)&Bs[r][c4<<2] = v;
    }
    __syncthreads();
    #pragma unroll
    for (int kk=0;kk<BK;++kk){
      float a[4], b[4];
      *(float4*)a = *(const float4*)&As[kk][tm];
      *(float4*)b = *(const float4*)&Bs[kk][tn];
      #pragma unroll
      for (int i=0;i<4;++i)
        #pragma unroll
        for (int j=0;j<4;++j) acc[i][j] = fmaf(a[i], b[j], acc[i][j]);
    }
    __syncthreads();
  }
  #pragma unroll
  for (int i=0;i<4;++i){
    int gr = bm+tm+i;
    if (gr < M){
      float4 o; o.x=acc[i][0]; o.y=acc[i][1]; o.z=acc[i][2]; o.w=acc[i][3];
      if (BIAS){
        o.x += bias[bn+tn+0]; o.y += bias[bn+tn+1];
        o.z += bias[bn+tn+2]; o.w += bias[bn+tn+3];
      }
      *(float4*)(C + (size_t)gr*N + bn + tn) = o;
    }
  }
}

// ---- W transpose + split: W[3072][128] -> Wth/Wtl[128][3072] bf16 hi/lo -------
__global__ __launch_bounds__(256) void wtprep(const float* __restrict__ W,
                                              ushort* __restrict__ Wth,
                                              ushort* __restrict__ Wtl){
  __shared__ float t[64][129];
  const int tid = threadIdx.x;
  const int kb = blockIdx.x*64;
  #pragma unroll
  for (int it=0; it<8; ++it){
    int cs = it*256 + tid;            // [0,2048)
    int kr = cs >> 5;                 // 32 float4 per 128-col row
    int c4 = cs & 31;
    float4 v = *(const float4*)(W + (size_t)(kb+kr)*128 + c4*4);
    t[kr][c4*4+0]=v.x; t[kr][c4*4+1]=v.y; t[kr][c4*4+2]=v.z; t[kr][c4*4+3]=v.w;
  }
  __syncthreads();
  #pragma unroll
  for (int it=0; it<4; ++it){
    int ch = it*256 + tid;            // [0,1024)
    int n  = ch >> 3;
    int k8 = (ch & 7)*8;
    s16x8 hv, lv;
    #pragma unroll
    for (int e=0;e<8;++e){
      float v = t[k8+e][n];
      ushort h = bfh(v);
      hv[e] = (short)h;
      lv[e] = (short)bfh(v - bf2f(h));
    }
    *(s16x8*)(Wth + (size_t)n*3072 + kb + k8) = hv;
    *(s16x8*)(Wtl + (size_t)n*3072 + kb + k8) = lv;
  }
}

// ---- lin partials: P[kc][m][n] = inputs[m, kc*384:(kc+1)*384] @ W[.., n] ------
__global__ __launch_bounds__(256,2) void lin_mfma(const float* __restrict__ Ain,
                                                  const ushort* __restrict__ Wth,
                                                  const ushort* __restrict__ Wtl,
                                                  float* __restrict__ P){
  extern __shared__ char lds[];          // 64 KiB: Ah@0 Al@16K Bh@32K Bl@48K
  ushort* ldsu = (ushort*)lds;
  const int tid = threadIdx.x, lane = tid&63, wave = tid>>6;
  const int wm = wave>>1, wn = wave&1;
  const int mt = blockIdx.x % 79, kc = blockIdx.x / 79;
  const int bm = mt*128;
  const int lr = lane&15, kq = lane>>4;
  f32x4 acc[4][4] = {};

  for (int st=0; st<6; ++st){
    const int kb = kc*384 + st*64;
    if (st) __syncthreads();
    #pragma unroll
    for (int it=0; it<8; ++it){
      int cs = it*256+tid, row = cs>>4, c4 = cs&15;
      int rg = bm+row; rg = rg < N_TOT ? rg : N_TOT-1;
      float4 v = *(const float4*)(Ain + (size_t)rg*3072 + kb + c4*4);
      ushort4 h, l;
      h.x=bfh(v.x); l.x=bfh(v.x-bf2f(h.x));
      h.y=bfh(v.y); l.y=bfh(v.y-bf2f(h.y));
      h.z=bfh(v.z); l.z=bfh(v.z-bf2f(h.z));
      h.w=bfh(v.w); l.w=bfh(v.w-bf2f(h.w));
      int bo = (c4*8) ^ ((row&7)<<4);
      *(ushort4*)(lds + row*128 + bo)         = h;
      *(ushort4*)(lds + 16384 + row*128 + bo) = l;
    }
    #pragma unroll
    for (int it=0; it<4; ++it){
      int cs = it*256+tid, row = cs>>3, slot = cs&7;
      int srcb = (slot*16) ^ ((row&7)<<4);
      gload16(Wth + (size_t)row*3072 + kb + (srcb>>1), ldsu + 16384 + cs*8);
      gload16(Wtl + (size_t)row*3072 + kb + (srcb>>1), ldsu + 24576 + cs*8);
    }
    __syncthreads();
    #pragma unroll
    for (int ks=0; ks<2; ++ks){
      const int kbyte = ks*64 + kq*16;
      s16x8 yh[4], yl[4];
      #pragma unroll
      for (int j=0;j<4;++j){
        int ma = wm*64 + j*16 + lr;
        int oa = ma*128 + (kbyte ^ ((ma&7)<<4));
        yh[j] = *(const s16x8*)(lds + oa);
        yl[j] = *(const s16x8*)(lds + 16384 + oa);
      }
      #pragma unroll
      for (int i=0;i<4;++i){
        int na = wn*64 + i*16 + lr;
        int ob = na*128 + (kbyte ^ ((na&7)<<4));
        s16x8 xh = *(const s16x8*)(lds + 32768 + ob);
        s16x8 xl = *(const s16x8*)(lds + 49152 + ob);
        #pragma unroll
        for (int j=0;j<4;++j){
          acc[i][j] = __builtin_amdgcn_mfma_f32_16x16x32_bf16(xh, yh[j], acc[i][j],0,0,0);
          acc[i][j] = __builtin_amdgcn_mfma_f32_16x16x32_bf16(xh, yl[j], acc[i][j],0,0,0);
          acc[i][j] = __builtin_amdgcn_mfma_f32_16x16x32_bf16(xl, yh[j], acc[i][j],0,0,0);
        }
      }
    }
  }
  #pragma unroll
  for (int j=0;j<4;++j){
    int m = bm + wm*64 + j*16 + lr;
    if (m < N_TOT){
      float* Pr = P + ((size_t)kc*N_TOT + m)*CDIM;
      #pragma unroll
      for (int i=0;i<4;++i)
        *(f32x4*)(Pr + wn*64 + i*16 + kq*4) = acc[i][j];
    }
  }
}

// ---- feat = bias + sum_kc P[kc] -----------------------------------------------
__global__ __launch_bounds__(256) void lin_reduce(const float* __restrict__ P,
                                                  const float* __restrict__ bias,
                                                  float* __restrict__ feat){
  int e = blockIdx.x*256 + threadIdx.x;      // 1,280,000 total
  float s = bias[e & 127];
  #pragma unroll
  for (int kc=0;kc<8;++kc) s += P[(size_t)kc*1280000 + e];
  feat[e] = s;
}

// ---------------- per-chunk BatchNorm (training stats, biased var), in place ----
__global__ __launch_bounds__(512) void bn_kernel(float* __restrict__ feat,
                                                 const float* __restrict__ g,
                                                 const float* __restrict__ b){
  int chunk = blockIdx.x;
  int c = threadIdx.x & 127, rq = threadIdx.x >> 7;
  __shared__ float S1[4][128], S2[4][128];
  float* base = feat + (size_t)chunk*100*CDIM;
  float s=0.f, s2=0.f;
  for (int r=rq*25; r<rq*25+25; ++r){ float v = base[r*CDIM+c]; s+=v; s2+=v*v; }
  S1[rq][c]=s; S2[rq][c]=s2;
  __syncthreads();
  if (rq==0){
    float ts = S1[0][c]+S1[1][c]+S1[2][c]+S1[3][c];
    float t2 = S2[0][c]+S2[1][c]+S2[2][c]+S2[3][c];
    float mu = ts*0.01f;
    float var = t2*0.01f - mu*mu;
    float sc = g[c]*rsqrtf(var+BN_EPS);
    S1[0][c] = sc; S2[0][c] = b[c] - mu*sc;
  }
  __syncthreads();
  float sc = S1[0][c], sh = S2[0][c];
  for (int r=rq*25; r<rq*25+25; ++r) base[r*CDIM+c] = base[r*CDIM+c]*sc + sh;
}

// ------- split feat into bf16 hi/lo (plain: fh/fl, a-scaled: gh/gl) + p, xn ----
__global__ __launch_bounds__(256) void featsplit(const float* __restrict__ feat,
                                                 const float* __restrict__ aS,
                                                 ushort* __restrict__ fh, ushort* __restrict__ fl,
                                                 ushort* __restrict__ gh, ushort* __restrict__ gl,
                                                 float* __restrict__ p, float* __restrict__ xn){
  int wave = threadIdx.x>>6, lane = threadIdx.x&63;
  int row = blockIdx.x*4 + wave;
  const float2 f = ((const float2*)(feat + (size_t)row*CDIM))[lane];
  const float2 a = ((const float2*)aS)[lane];
  float gx = f.x*a.x, gy = f.y*a.y;

  ushort2 v;
  size_t o = (size_t)row*64 + lane;
  v.x = bfh(f.x); v.y = bfh(f.y);
  ((ushort2*)fh)[o] = v;
  ushort2 vl; vl.x = bfh(f.x - bf2f(v.x)); vl.y = bfh(f.y - bf2f(v.y));
  ((ushort2*)fl)[o] = vl;
  ushort2 w; w.x = bfh(gx); w.y = bfh(gy);
  ((ushort2*)gh)[o] = w;
  ushort2 wl2; wl2.x = bfh(gx - bf2f(w.x)); wl2.y = bfh(gy - bf2f(w.y));
  ((ushort2*)gl)[o] = wl2;

  float sp = gx*f.x + gy*f.y;
  float sx = f.x*f.x + f.y*f.y;
  sp = waveSumF(sp); sx = waveSumF(sx);
  if (lane==0){ p[row]=sp; xn[row]=sx; }
}

// -------- scores[i][j] = relu(p_i + p_j + b - 2*(g_i . f_j)), split-bf16 MFMA --
__global__ __launch_bounds__(256,2) void score_mfma(const ushort* __restrict__ fh,
                                                    const ushort* __restrict__ fl,
                                                    const ushort* __restrict__ gh,
                                                    const ushort* __restrict__ gl,
                                                    const float* __restrict__ p,
                                                    const float* __restrict__ bS,
                                                    float* __restrict__ scores){
  extern __shared__ char lds[];        // 64 KiB: Gh@0 Gl@16K Fh@32K Fl@48K
  ushort* ldsu = (ushort*)lds;
  const int tid  = threadIdx.x;
  const int lane = tid & 63;
  const int wave = tid >> 6;
  const int wm = wave >> 1, wn = wave & 1;

  const int nwg = 6241, q = nwg >> 3, r = nwg & 7;   // q=780, r=1
  int bid = blockIdx.x;
  int xcd = bid & 7, loc = bid >> 3;
  int wid = (xcd < r ? xcd*(q+1) : r*(q+1) + (xcd-r)*q) + loc;
  const int bxt = wid / 79;
  const int byt = wid % 79;
  const int bm = byt*128;
  const int bn = bxt*128;
  const int lr = lane & 15;
  const int kq = lane >> 4;
  f32x4 acc[4][4] = {};

  for (int ko=0; ko<2; ++ko){
    const int k0 = ko*64;
    if (ko) __syncthreads();
    #define STG(SRC, RB, UOFF)                                                  \
      { _Pragma("unroll")                                                       \
        for (int it=0; it<4; ++it){                                             \
          int cs = it*256 + tid;                                                \
          int row = cs >> 3;                                                    \
          int srcb = ((cs & 7) << 4) ^ ((row & 7) << 4);                        \
          int rg = (RB) + row; rg = (rg < N_TOT ? rg : N_TOT-1);                \
          gload16(SRC + (size_t)rg*CDIM + k0 + (srcb >> 1),                     \
                  ldsu + (UOFF) + cs*8);                                        \
        } }
    STG(gh, bm, 0)
    STG(gl, bm, 8192)
    STG(fh, bn, 16384)
    STG(fl, bn, 24576)
    #undef STG
    __syncthreads();

    #pragma unroll
    for (int ks=0; ks<2; ++ks){
      const int kbyte = ks*64 + kq*16;
      s16x8 yh[4], yl[4];
      #pragma unroll
      for (int j=0;j<4;++j){
        int ca = wn*64 + j*16 + lr;
        int ob = ca*128 + (kbyte ^ ((ca&7)<<4));
        yh[j] = *(const s16x8*)(lds + 32768 + ob);
        yl[j] = *(const s16x8*)(lds + 49152 + ob);
      }
      #pragma unroll
      for (int i=0;i<4;++i){
        int ra = wm*64 + i*16 + lr;
        int oa = ra*128 + (kbyte ^ ((ra&7)<<4));
        s16x8 xh = *(const s16x8*)(lds + oa);
        s16x8 xl = *(const s16x8*)(lds + 16384 + oa);
        #pragma unroll
        for (int j=0;j<4;++j){
          acc[i][j] = __builtin_amdgcn_mfma_f32_16x16x32_bf16(xh, yh[j], acc[i][j],0,0,0);
          acc[i][j] = __builtin_amdgcn_mfma_f32_16x16x32_bf16(xh, yl[j], acc[i][j],0,0,0);
          acc[i][j] = __builtin_amdgcn_mfma_f32_16x16x32_bf16(xl, yh[j], acc[i][j],0,0,0);
        }
      }
    }
  }

  const float bb = bS[0];
  float pj[4];
  #pragma unroll
  for (int j=0;j<4;++j){
    int col = bn + wn*64 + j*16 + lr;
    pj[j] = p[col < N_TOT ? col : N_TOT-1];
  }
  #pragma unroll
  for (int i=0;i<4;++i){
    #pragma unroll
    for (int rr=0;rr<4;++rr){
      int row = bm + wm*64 + i*16 + kq*4 + rr;
      if (row < N_TOT){
        float pi = p[row];
        #pragma unroll
        for (int j=0;j<4;++j){
          int col = bn + wn*64 + j*16 + lr;
          if (col < N_TOT)
            scores[(size_t)row*N_TOT + col] = fmaxf(pi + pj[j] + bb - 2.f*acc[i][j][rr], 0.f);
        }
      }
    }
  }
}

// ------ exact per-row top-50 + softmax, FUSED with S-row zero + scatter --------
// Each block owns row i: reads scores row (which lives IN the S region), selects
// top-50, then overwrites its own row with zeros + scattered softmax values.
__global__ __launch_bounds__(256) void topk_kernel(float* __restrict__ SrowsBase,
                                                   int* __restrict__ idxO,
                                                   float* __restrict__ softO){
  const int row = blockIdx.x, tid = threadIdx.x;
  float* srowW = SrowsBase + (size_t)row*N_TOT;     // base is Sout (out+100001)
  const float4* srow = (const float4*)srowW;        // reads: rows are scratch
  // NOTE: reads use the same rows; row start is only 4B-aligned in the true S
  // layout, but scores were WRITTEN at scratch base out+100000 row-major, so
  // reading here must match the scratch layout. We keep scratch == Sout row
  // layout by writing scores at Sout too (see launch).
  float4 v[10];
  #pragma unroll
  for (int s=0;s<10;++s){
    int fi = tid + s*256;
    // rows are 4B-aligned (base offset 100001); do scalar-safe vector loads:
    if (fi < 2500){
      const float* pr = srowW + fi*4;
      v[s].x = pr[0]; v[s].y = pr[1]; v[s].z = pr[2]; v[s].w = pr[3];
    } else v[s] = make_float4(-1.f,-1.f,-1.f,-1.f);
  }
  float mx = -1.f;
  #pragma unroll
  for (int s=0;s<10;++s)
    mx = fmaxf(mx, fmaxf(fmaxf(v[s].x,v[s].y), fmaxf(v[s].z,v[s].w)));
  __shared__ float redf[4];
  __shared__ int cntS;
  float wm = waveMaxF(mx);
  if ((tid&63)==0) redf[tid>>6] = wm;
  __syncthreads();
  mx = fmaxf(fmaxf(redf[0],redf[1]), fmaxf(redf[2],redf[3]));

  unsigned lo = 0, hi = __float_as_uint(mx);
  while (lo < hi){
    unsigned mid = (lo + hi) >> 1;
    float t = __uint_as_float(mid);
    int c = 0;
    #pragma unroll
    for (int s=0;s<10;++s)
      c += (v[s].x>t) + (v[s].y>t) + (v[s].z>t) + (v[s].w>t);
    if (tid==0) cntS = 0;
    __syncthreads();
    c = waveSumI(c);
    if ((tid&63)==0) atomicAdd(&cntS, c);
    __syncthreads();
    int total = cntS;
    __syncthreads();
    if (total >= TK) lo = mid + 1; else hi = mid;
  }
  const float v50 = __uint_as_float(lo);

  __shared__ int   selIdx[TK];
  __shared__ float selVal[TK];
  __shared__ float softS[TK];
  __shared__ int cSel, cTie;
  if (tid==0){ cSel=0; cTie=0; }
  __syncthreads();
  #pragma unroll
  for (int s=0;s<10;++s){
    int base = 4*(tid + s*256);
    float vals[4] = {v[s].x, v[s].y, v[s].z, v[s].w};
    #pragma unroll
    for (int e=0;e<4;++e){
      if (vals[e] > v50){ int q = atomicAdd(&cSel,1); selIdx[q]=base+e; selVal[q]=vals[e]; }
    }
  }
  __syncthreads();
  const int m = cSel;
  #pragma unroll
  for (int s=0;s<10;++s){
    int base = 4*(tid + s*256);
    float vals[4] = {v[s].x, v[s].y, v[s].z, v[s].w};
    #pragma unroll
    for (int e=0;e<4;++e){
      if (vals[e] == v50){
        int q = atomicAdd(&cTie,1);
        if (m + q < TK){ selIdx[m+q]=base+e; selVal[m+q]=v50; }
      }
    }
  }
  __syncthreads();
  if (tid < 64){
    float e = (tid < TK) ? __expf(selVal[tid] - mx) : 0.f;
    float s = waveSumF(e);
    if (tid < TK){
      float sv = e / s;
      softO[row*TK + tid] = sv;
      idxO [row*TK + tid] = selIdx[tid];
      softS[tid] = sv;
    }
  }
  // ---- zero own S row (3 scalar + 2499 float4 + 1 scalar; base ≡1 mod 4) ----
  if (tid < 3) srowW[tid] = 0.f;
  {
    float4* s4 = (float4*)(srowW + 3);     // 16B-aligned
    const float4 z = make_float4(0,0,0,0);
    #pragma unroll
    for (int it=0; it<10; ++it){
      int i = tid + it*256;
      if (i < 2499) s4[i] = z;
    }
  }
  if (tid == 0) srowW[9999] = 0.f;
  __syncthreads();
  // ---- scatter softmax values ----
  if (tid < TK) srowW[selIdx[tid]] = softS[tid];
}

// ---------------- loss = sum(dp*soft) + gamma*sum(soft) (into 256 slots) -------
__global__ __launch_bounds__(256) void loss_kernel(const float* __restrict__ feat,
                                                   const float* __restrict__ xn,
                                                   const int* __restrict__ idx,
                                                   const float* __restrict__ soft,
                                                   float* __restrict__ slots){
  int row = blockIdx.x;
  int grp = threadIdx.x>>6, lane = threadIdx.x&63;
  const float2 a = ((const float2*)(feat + (size_t)row*CDIM))[lane];
  float acc = 0.f;
  for (int k=grp; k<TK; k+=4){
    int   j = idx [row*TK + k];
    float s = soft[row*TK + k];
    const float2 b = ((const float2*)(feat + (size_t)j*CDIM))[lane];
    float d = a.x*b.x + a.y*b.y;
    d = waveSumF(d);
    if (lane==0){
      float dp = fmaxf(xn[row] + xn[j] - 2.f*d, 0.f);
      acc += s*dp + GAMMA_REG*s;
    }
  }
  __shared__ float part[4];
  if (lane==0) part[grp] = acc;
  __syncthreads();
  if (threadIdx.x==0) atomicAdd(&slots[row & 255], part[0]+part[1]+part[2]+part[3]);
}

__global__ void loss_finish(const float* __restrict__ slots, float* __restrict__ lossOut){
  float v = slots[threadIdx.x];
  v = waveSumF(v);
  __shared__ float pp[4];
  if ((threadIdx.x&63)==0) pp[threadIdx.x>>6] = v;
  __syncthreads();
  if (threadIdx.x==0) lossOut[0] = pp[0]+pp[1]+pp[2]+pp[3];
}

// ---------------- h[i][c] = relu(b1[c] + sum_k soft * X1[idx_k][c]) ------------
__global__ __launch_bounds__(256) void h_kernel(const float* __restrict__ X1,
                                                const int* __restrict__ idx,
                                                const float* __restrict__ soft,
                                                const float* __restrict__ b1,
                                                float* __restrict__ h){
  int row = blockIdx.x, c = threadIdx.x;
  __shared__ int   ji[TK];
  __shared__ float sv[TK];
  if (c < TK){ ji[c]=idx[row*TK+c]; sv[c]=soft[row*TK+c]; }
  __syncthreads();
  float acc = b1[c];
  #pragma unroll 10
  for (int k=0;k<TK;++k) acc = fmaf(sv[k], X1[(size_t)ji[k]*NHID_ + c], acc);
  h[(size_t)row*NHID_ + c] = fmaxf(acc, 0.f);
}

// ---------------- X2 = h @ W2 (W2 in LDS) --------------------------------------
__global__ __launch_bounds__(256) void x2_kernel(const float* __restrict__ h,
                                                 const float* __restrict__ W2,
                                                 float* __restrict__ X2){
  __shared__ float w[NHID_*NCLS];
  for (int i=threadIdx.x; i<NHID_*NCLS; i+=256) w[i] = W2[i];
  __syncthreads();
  int t = blockIdx.x*256 + threadIdx.x;
  if (t < N_TOT*NCLS){
    int r = t / NCLS, c = t % NCLS;
    float acc = 0.f;
    const float* hr = h + (size_t)r*NHID_;
    #pragma unroll 8
    for (int k=0;k<NHID_;++k) acc = fmaf(hr[k], w[k*NCLS+c], acc);
    X2[t] = acc;
  }
}

// ------- logits[i][c] = b2[c] + sum_k soft*X2[idx_k][c]; semi = log_softmax ----
__global__ __launch_bounds__(64) void logits_kernel(const float* __restrict__ X2,
                                                    const int* __restrict__ idx,
                                                    const float* __restrict__ soft,
                                                    const float* __restrict__ b2,
                                                    float* __restrict__ semi){
  int row = blockIdx.x, tid = threadIdx.x;
  __shared__ int   ji[TK];
  __shared__ float sv[TK];
  if (tid < TK){ ji[tid]=idx[row*TK+tid]; sv[tid]=soft[row*TK+tid]; }
  __syncthreads();
  float acc = 0.f;
  if (tid < NCLS){
    acc = b2[tid];
    for (int k=0;k<TK;++k) acc = fmaf(sv[k], X2[(size_t)ji[k]*NCLS + tid], acc);
  }
  float mv = (tid < NCLS) ? acc : -1e30f;
  #pragma unroll
  for (int o=8;o;o>>=1) mv = fmaxf(mv, __shfl_xor(mv,o,16));
  float e = (tid < NCLS) ? __expf(acc - mv) : 0.f;
  #pragma unroll
  for (int o=8;o;o>>=1) e += __shfl_xor(e,o,16);
  if (tid < NCLS) semi[row*NCLS + tid] = acc - mv - logf(e);
}

extern "C" void kernel_launch(void* const* d_in, const int* in_sizes, int n_in,
                              void* d_out, int out_size, void* d_ws, size_t ws_size,
                              hipStream_t stream){
  const float* inputs   = (const float*)d_in[0];
  const float* W_lin    = (const float*)d_in[1];
  const float* b_lin    = (const float*)d_in[2];
  const float* bn_gamma = (const float*)d_in[3];
  const float* bn_beta  = (const float*)d_in[4];
  const float* a_S      = (const float*)d_in[5];
  const float* b_S      = (const float*)d_in[6];
  const float* W1       = (const float*)d_in[7];
  const float* b1       = (const float*)d_in[8];
  const float* W2       = (const float*)d_in[9];
  const float* b2       = (const float*)d_in[10];

  float* out  = (float*)d_out;
  float* ws   = (float*)d_ws;

  float*  feat = ws;                        // [0        .. 1,280,000)
  float*  p    = ws + 1280000;
  float*  xn   = ws + 1290000;
  int*    idxb = (int*)(ws + 1300000);      // 500,000
  float*  soft = ws + 1800000;              // 500,000
  float*  X1   = ws + 2300000;              // 2,560,000
  ushort* fh   = (ushort*)(ws + 4860000);   // 640,000 f each
  ushort* fl   = (ushort*)(ws + 5500000);
  ushort* gh   = (ushort*)(ws + 6140000);
  ushort* gl   = (ushort*)(ws + 6780000);
  float*  hbuf = ws + 4860000;              // reuse of split region (after score)
  float*  X2   = ws + 7420000;              // 100,000
  float*  lossSlots = ws + 7520000;         // 256

  // d_out layout: semi[100000], loss[1], S[1e8]
  float* semi    = out;
  float* lossOut = out + 100000;
  float* Sout    = out + 100001;            // scores are written HERE (row-major,
                                            // same layout as final S) and then
                                            // zero+scatter'd in-place by topk.

  // lin-phase scratch inside the S region (dead before score_mfma runs)
  const size_t SC = 100004;
  ushort* Wth  = (ushort*)(out + SC);                 // 393,216 ushorts
  ushort* Wtl  = (ushort*)(out + SC + 196608);
  float*  Part = out + SC + 393216;                   // 8 x 1,280,000 floats

  // 1. W transpose+split; lin partials via split-bf16 MFMA; reduce + bias
  wtprep<<<48, 256, 0, stream>>>(W_lin, Wth, Wtl);
  lin_mfma<<<632, 256, 65536, stream>>>(inputs, Wth, Wtl, Part);
  lin_reduce<<<5000, 256, 0, stream>>>(Part, b_lin, feat);
  // 2. per-chunk BN in place
  bn_kernel<<<100, 512, 0, stream>>>(feat, bn_gamma, bn_beta);
  // 3. bf16 splits + p, xn
  featsplit<<<2500, 256, 0, stream>>>(feat, a_S, fh, fl, gh, gl, p, xn);
  // 4. scores via two-phase LDS-staged split-bf16 MFMA -> Sout (in-place scratch)
  score_mfma<<<6241, 256, 65536, stream>>>(fh, fl, gh, gl, p, b_S, Sout);
  // 5. X1 = feat @ W1
  gemm64<false><<<dim3(4,157), 256, 0, stream>>>(feat, W1, nullptr, X1, N_TOT, NHID_, CDIM);
  // 6. top-50 + softmax + in-place S-row zero + scatter (fused)
  topk_kernel<<<N_TOT, 256, 0, stream>>>(Sout, idxb, soft);
  // 7. zero the 256 loss slots only (tiny)
  hipMemsetAsync(lossSlots, 0, 256*sizeof(float), stream);
  // 8. loss
  loss_kernel<<<N_TOT, 256, 0, stream>>>(feat, xn, idxb, soft, lossSlots);
  loss_finish<<<1, 256, 0, stream>>>(lossSlots, lossOut);
  // 9. h = relu(S@X1 + b1)  (hbuf overwrites dead split buffers)
  h_kernel<<<N_TOT, NHID_, 0, stream>>>(X1, idxb, soft, b1, hbuf);
  // 10. X2 = h @ W2
  x2_kernel<<<(N_TOT*NCLS+255)/256, 256, 0, stream>>>(hbuf, W2, X2);
  // 11. logits + log_softmax
  logits_kernel<<<N_TOT, 64, 0, stream>>>(X2, idxb, soft, b2, semi);
}